// Round 1
// baseline (358.597 us; speedup 1.0000x reference)
//
#include <hip/hip_runtime.h>
#include <hip/hip_bf16.h>

#define T_TOK 4096
#define H_DIM 512
#define I_DIM 1024
#define E_NUM 32
#define KTOP  2
#define CAP   512
#define NROWS (E_NUM * CAP)    // 16384
#define NPAIR (T_TOK * KTOP)   // 8192

typedef __attribute__((ext_vector_type(8))) short short8;    // 8 bf16 = 4 VGPRs
typedef __attribute__((ext_vector_type(4))) float float4v;
typedef __attribute__((ext_vector_type(4))) unsigned int uint4v;

__device__ __forceinline__ unsigned short f2bf_rne(float f) {
  unsigned int u = __float_as_uint(f);
  u += 0x7FFFu + ((u >> 16) & 1u);
  return (unsigned short)(u >> 16);
}
__device__ __forceinline__ unsigned int pack_bf2(float a, float b) {
  return (unsigned int)f2bf_rne(a) | ((unsigned int)f2bf_rne(b) << 16);
}

#define GLOAD_LDS16(gptr, lptr)                                                         \
  __builtin_amdgcn_global_load_lds((const __attribute__((address_space(1))) unsigned int*)(gptr), \
                                   (__attribute__((address_space(3))) unsigned int*)(lptr), 16, 0, 0)

// ---------------- init: zero output + counts ----------------
__global__ void k_init(float4v* __restrict__ out4, int* __restrict__ counts) {
  int gi = blockIdx.x * 256 + threadIdx.x;
  if (gi < E_NUM) counts[gi] = 0;
  float4v z = {0.f, 0.f, 0.f, 0.f};
  out4[gi] = z;  // grid sized exactly: T*H/4 elements
}

// ---------------- routing ----------------
__global__ void k_route(const int* __restrict__ idx, const float* __restrict__ wts,
                        int* __restrict__ counts, int* __restrict__ slot_token,
                        float* __restrict__ slot_w) {
  int i = blockIdx.x * 256 + threadIdx.x;
  if (i >= NPAIR) return;
  int e = idx[i];
  int p = atomicAdd(counts + e, 1);
  if (p < CAP) {
    slot_token[e * CAP + p] = i >> 1;  // KTOP == 2
    slot_w[e * CAP + p] = wts[i];
  }
}

// ---------------- gather tokens -> bf16 dispatch buffer ----------------
__global__ void k_gather(const float* __restrict__ hs, const int* __restrict__ counts,
                         const int* __restrict__ slot_token, unsigned short* __restrict__ xd) {
  const int r = blockIdx.x * 4 + (threadIdx.x >> 6);  // one wave per row
  const int lane = threadIdx.x & 63;
  const int e = r >> 9;
  const int p = r & (CAP - 1);
  uint4v v = {0u, 0u, 0u, 0u};
  if (p < counts[e]) {
    const int t = slot_token[r];
    const float4v* src = (const float4v*)(hs + (size_t)t * H_DIM);
    float4v f0 = src[lane * 2];
    float4v f1 = src[lane * 2 + 1];
    v.x = pack_bf2(f0.x, f0.y);
    v.y = pack_bf2(f0.z, f0.w);
    v.z = pack_bf2(f1.x, f1.y);
    v.w = pack_bf2(f1.z, f1.w);
  }
  *(uint4v*)(xd + (size_t)r * H_DIM + lane * 8) = v;
}

// ---------------- GEMM1: xd[NROWS,H] x gate_up[E,2I,H]^T -> silu(g)*u -> act[NROWS,I] ----
// 128x128 tile (gate cols) + the matching 128 up cols. BK=32. 4 waves 2x2, each 64x64.
// LDS k-plane-major layout [kc][row][8] -> conflict-free b128 reads, global_load_lds-compatible.
__global__ __launch_bounds__(256, 2) void k_gemm1(const unsigned short* __restrict__ xd,
                                                  const float* __restrict__ gup,
                                                  unsigned short* __restrict__ act) {
  __shared__ unsigned short lds_a[4 * 128 * 8];
  __shared__ unsigned short lds_bg[4 * 128 * 8];
  __shared__ unsigned short lds_bu[4 * 128 * 8];

  const int tid = threadIdx.x;
  const int lane = tid & 63;
  const int wid = tid >> 6;
  const int wr = wid >> 1, wc = wid & 1;
  const int ml = lane & 15, kg = lane >> 4;

  const int c0 = blockIdx.x * 128;  // gate col base (0..I)
  const int r0 = blockIdx.y * 128;  // row base
  const int e = r0 >> 9;

  const float* bg_base = gup + (size_t)e * (2 * I_DIM * H_DIM) + (size_t)c0 * H_DIM;
  const float* bu_base = bg_base + (size_t)I_DIM * H_DIM;

  float4v accg[4][4] = {};
  float4v accu[4][4] = {};

  for (int kk = 0; kk < H_DIM; kk += 32) {
    // A tile: 512 16B-chunks, async direct-to-LDS
#pragma unroll
    for (int q = 0; q < 2; ++q) {
      int ch = q * 256 + wid * 64 + lane;
      int kc = ch >> 7, row = ch & 127;
      const unsigned short* g = xd + (size_t)(r0 + row) * H_DIM + kk + kc * 8;
      unsigned short* l = lds_a + (size_t)(q * 256 + wid * 64) * 8;  // wave-uniform base
      GLOAD_LDS16(g, l);
    }
    // B tiles (fp32 -> bf16): chunk c -> n=c>>2, kc=c&3 (coalesced 128B/4-lane reads)
#pragma unroll
    for (int q = 0; q < 2; ++q) {
      int c = q * 256 + tid;
      int n = c >> 2, kc = c & 3;
      {
        const float* g = bg_base + (size_t)n * H_DIM + kk + kc * 8;
        float4v f0 = *(const float4v*)g;
        float4v f1 = *(const float4v*)(g + 4);
        uint4v v;
        v.x = pack_bf2(f0.x, f0.y); v.y = pack_bf2(f0.z, f0.w);
        v.z = pack_bf2(f1.x, f1.y); v.w = pack_bf2(f1.z, f1.w);
        *(uint4v*)(lds_bg + (size_t)(kc * 128 + n) * 8) = v;
      }
      {
        const float* g = bu_base + (size_t)n * H_DIM + kk + kc * 8;
        float4v f0 = *(const float4v*)g;
        float4v f1 = *(const float4v*)(g + 4);
        uint4v v;
        v.x = pack_bf2(f0.x, f0.y); v.y = pack_bf2(f0.z, f0.w);
        v.z = pack_bf2(f1.x, f1.y); v.w = pack_bf2(f1.z, f1.w);
        *(uint4v*)(lds_bu + (size_t)(kc * 128 + n) * 8) = v;
      }
    }
    __syncthreads();

    short8 af[4], bgf[4], buf_[4];
#pragma unroll
    for (int mi = 0; mi < 4; ++mi)
      af[mi] = *(const short8*)(lds_a + (size_t)(kg * 128 + wr * 64 + mi * 16 + ml) * 8);
#pragma unroll
    for (int ni = 0; ni < 4; ++ni) {
      bgf[ni] = *(const short8*)(lds_bg + (size_t)(kg * 128 + wc * 64 + ni * 16 + ml) * 8);
      buf_[ni] = *(const short8*)(lds_bu + (size_t)(kg * 128 + wc * 64 + ni * 16 + ml) * 8);
    }
#pragma unroll
    for (int mi = 0; mi < 4; ++mi)
#pragma unroll
      for (int ni = 0; ni < 4; ++ni) {
        accg[mi][ni] = __builtin_amdgcn_mfma_f32_16x16x32_bf16(af[mi], bgf[ni], accg[mi][ni], 0, 0, 0);
        accu[mi][ni] = __builtin_amdgcn_mfma_f32_16x16x32_bf16(af[mi], buf_[ni], accu[mi][ni], 0, 0, 0);
      }
    __syncthreads();
  }

  // epilogue: act = silu(g)*u, bf16
#pragma unroll
  for (int mi = 0; mi < 4; ++mi) {
    int row = r0 + wr * 64 + mi * 16 + kg * 4;
#pragma unroll
    for (int ni = 0; ni < 4; ++ni) {
      int col = c0 + wc * 64 + ni * 16 + ml;
#pragma unroll
      for (int rg = 0; rg < 4; ++rg) {
        float g = accg[mi][ni][rg];
        float u = accu[mi][ni][rg];
        float a = (g / (1.0f + __expf(-g))) * u;
        act[(size_t)(row + rg) * I_DIM + col] = f2bf_rne(a);
      }
    }
  }
}

// ---------------- GEMM2: act[NROWS,I] x down[E,H,I]^T -> weighted atomic scatter to out ----
__global__ __launch_bounds__(256, 2) void k_gemm2(const unsigned short* __restrict__ act,
                                                  const float* __restrict__ dwn,
                                                  const int* __restrict__ counts,
                                                  const int* __restrict__ slot_token,
                                                  const float* __restrict__ slot_w,
                                                  float* __restrict__ out) {
  __shared__ unsigned short lds_a[4 * 128 * 8];
  __shared__ unsigned short lds_b[4 * 128 * 8];
  __shared__ int s_tok[128];
  __shared__ float s_w[128];

  const int tid = threadIdx.x;
  const int lane = tid & 63;
  const int wid = tid >> 6;
  const int wr = wid >> 1, wc = wid & 1;
  const int ml = lane & 15, kg = lane >> 4;

  const int c0 = blockIdx.x * 128;  // h col base (0..H)
  const int r0 = blockIdx.y * 128;  // row base
  const int e = r0 >> 9;

  if (tid < 128) {
    s_tok[tid] = slot_token[r0 + tid];
    s_w[tid] = slot_w[r0 + tid];
  }

  const float* b_base = dwn + (size_t)e * (H_DIM * I_DIM) + (size_t)c0 * I_DIM;

  float4v acc[4][4] = {};

  for (int kk = 0; kk < I_DIM; kk += 32) {
#pragma unroll
    for (int q = 0; q < 2; ++q) {
      int ch = q * 256 + wid * 64 + lane;
      int kc = ch >> 7, row = ch & 127;
      const unsigned short* g = act + (size_t)(r0 + row) * I_DIM + kk + kc * 8;
      unsigned short* l = lds_a + (size_t)(q * 256 + wid * 64) * 8;
      GLOAD_LDS16(g, l);
    }
    {
      int c = tid;  // 512 chunks over 256 threads -> 2 each
#pragma unroll
      for (int q = 0; q < 2; ++q) {
        int cc = q * 256 + c;
        int n = cc >> 2, kc = cc & 3;
        const float* g = b_base + (size_t)n * I_DIM + kk + kc * 8;
        float4v f0 = *(const float4v*)g;
        float4v f1 = *(const float4v*)(g + 4);
        uint4v v;
        v.x = pack_bf2(f0.x, f0.y); v.y = pack_bf2(f0.z, f0.w);
        v.z = pack_bf2(f1.x, f1.y); v.w = pack_bf2(f1.z, f1.w);
        *(uint4v*)(lds_b + (size_t)(kc * 128 + n) * 8) = v;
      }
    }
    __syncthreads();

    short8 af[4], bf[4];
#pragma unroll
    for (int mi = 0; mi < 4; ++mi)
      af[mi] = *(const short8*)(lds_a + (size_t)(kg * 128 + wr * 64 + mi * 16 + ml) * 8);
#pragma unroll
    for (int ni = 0; ni < 4; ++ni)
      bf[ni] = *(const short8*)(lds_b + (size_t)(kg * 128 + wc * 64 + ni * 16 + ml) * 8);
#pragma unroll
    for (int mi = 0; mi < 4; ++mi)
#pragma unroll
      for (int ni = 0; ni < 4; ++ni)
        acc[mi][ni] = __builtin_amdgcn_mfma_f32_16x16x32_bf16(af[mi], bf[ni], acc[mi][ni], 0, 0, 0);
    __syncthreads();
  }

  const int cnt = counts[e];
#pragma unroll
  for (int mi = 0; mi < 4; ++mi) {
    int rbase = wr * 64 + mi * 16 + kg * 4;
#pragma unroll
    for (int rg = 0; rg < 4; ++rg) {
      int rloc = rbase + rg;
      int p = (r0 + rloc) & (CAP - 1);
      if (p < cnt) {
        int t = s_tok[rloc];
        float w = s_w[rloc];
#pragma unroll
        for (int ni = 0; ni < 4; ++ni) {
          int col = c0 + wc * 64 + ni * 16 + ml;
          atomicAdd(out + (size_t)t * H_DIM + col, acc[mi][ni][rg] * w);
        }
      }
    }
  }
}

extern "C" void kernel_launch(void* const* d_in, const int* in_sizes, int n_in,
                              void* d_out, int out_size, void* d_ws, size_t ws_size,
                              hipStream_t stream) {
  const float* hs  = (const float*)d_in[0];  // [T,H]
  const int*   idx = (const int*)d_in[1];    // [T,K] int32
  const float* wts = (const float*)d_in[2];  // [T,K]
  const float* gup = (const float*)d_in[3];  // [E,2I,H]
  const float* dwn = (const float*)d_in[4];  // [E,H,I]
  float* out = (float*)d_out;                // [T,H]

  char* ws = (char*)d_ws;
  int*   counts     = (int*)ws;                                  // 32 ints (256B slot)
  int*   slot_token = (int*)(ws + 256);                          // 64 KB
  float* slot_w     = (float*)(ws + 256 + 65536);                // 64 KB
  unsigned short* xd  = (unsigned short*)(ws + 256 + 2 * 65536); // 16 MB
  unsigned short* act = xd + (size_t)NROWS * H_DIM;              // 32 MB

  k_init<<<(T_TOK * H_DIM / 4) / 256, 256, 0, stream>>>((float4v*)out, counts);
  k_route<<<NPAIR / 256, 256, 0, stream>>>(idx, wts, counts, slot_token, slot_w);
  k_gather<<<NROWS / 4, 256, 0, stream>>>(hs, counts, slot_token, xd);
  dim3 g1(I_DIM / 128, NROWS / 128);
  k_gemm1<<<g1, 256, 0, stream>>>(xd, gup, act);
  dim3 g2(H_DIM / 128, NROWS / 128);
  k_gemm2<<<g2, 256, 0, stream>>>(act, dwn, counts, slot_token, slot_w, out);
}

// Round 2
// 353.155 us; speedup vs baseline: 1.0154x; 1.0154x over previous
//
#include <hip/hip_runtime.h>
#include <hip/hip_bf16.h>

#define T_TOK 4096
#define H_DIM 512
#define I_DIM 1024
#define E_NUM 32
#define KTOP  2
#define CAP   512
#define NROWS (E_NUM * CAP)    // 16384
#define NPAIR (T_TOK * KTOP)   // 8192

typedef __attribute__((ext_vector_type(8))) short short8;    // 8 bf16 = 4 VGPRs
typedef __attribute__((ext_vector_type(4))) float float4v;
typedef __attribute__((ext_vector_type(4))) unsigned int uint4v;

__device__ __forceinline__ unsigned short f2bf_rne(float f) {
  unsigned int u = __float_as_uint(f);
  u += 0x7FFFu + ((u >> 16) & 1u);
  return (unsigned short)(u >> 16);
}
__device__ __forceinline__ unsigned int pack_bf2(float a, float b) {
  return (unsigned int)f2bf_rne(a) | ((unsigned int)f2bf_rne(b) << 16);
}
__device__ __forceinline__ float bf2f(unsigned short s) {
  return __uint_as_float(((unsigned int)s) << 16);
}

#define GLOAD_LDS16(gptr, lptr)                                                         \
  __builtin_amdgcn_global_load_lds((const __attribute__((address_space(1))) unsigned int*)(gptr), \
                                   (__attribute__((address_space(3))) unsigned int*)(lptr), 16, 0, 0)

// XOR swizzle for B tiles: chunk (kc in 0..3, n in 0..127) -> 16B-chunk index.
// Within any 16-lane write phase (n0..n0+3 x kc0..3) each 8-chunk bank column is
// hit exactly 2x (2-way = free, m136). Reads stay contiguous-per-16-lanes.
#define SWZ(kc, n) (((kc) << 7) | ((n) ^ ((kc) << 1)))

// ---------------- routing ----------------
__global__ void k_route(const int* __restrict__ idx, int* __restrict__ counts,
                        int* __restrict__ slot_token, int* __restrict__ inv) {
  int i = blockIdx.x * 256 + threadIdx.x;
  if (i >= NPAIR) return;
  int e = idx[i];
  int p = atomicAdd(counts + e, 1);
  if (p < CAP) {
    slot_token[e * CAP + p] = i >> 1;  // KTOP == 2
    inv[i] = e * CAP + p;
  } else {
    inv[i] = -1;
  }
}

// ---------------- gather tokens -> bf16 dispatch buffer (early-exit padded rows) ----
__global__ void k_gather(const float* __restrict__ hs, const int* __restrict__ counts,
                         const int* __restrict__ slot_token, unsigned short* __restrict__ xd) {
  const int r = blockIdx.x * 4 + (threadIdx.x >> 6);  // one wave per row
  const int lane = threadIdx.x & 63;
  const int e = r >> 9;
  const int p = r & (CAP - 1);
  const int cnt = min(counts[e], CAP);
  if (p >= ((cnt + 127) & ~127)) return;  // beyond last active tile: never read
  uint4v v = {0u, 0u, 0u, 0u};
  if (p < cnt) {
    const int t = slot_token[r];
    const float4v* src = (const float4v*)(hs + (size_t)t * H_DIM);
    float4v f0 = src[lane * 2];
    float4v f1 = src[lane * 2 + 1];
    v.x = pack_bf2(f0.x, f0.y);
    v.y = pack_bf2(f0.z, f0.w);
    v.z = pack_bf2(f1.x, f1.y);
    v.w = pack_bf2(f1.z, f1.w);
  }
  *(uint4v*)(xd + (size_t)r * H_DIM + lane * 8) = v;
}

// ---------------- GEMM1: xd[NROWS,H] x gate_up[E,2I,H]^T -> silu(g)*u -> act[NROWS,I] ----
__global__ __launch_bounds__(256, 2) void k_gemm1(const unsigned short* __restrict__ xd,
                                                  const float* __restrict__ gup,
                                                  const int* __restrict__ counts,
                                                  unsigned short* __restrict__ act) {
  __shared__ unsigned short lds_a[4 * 128 * 8];
  __shared__ unsigned short lds_bg[4 * 128 * 8];
  __shared__ unsigned short lds_bu[4 * 128 * 8];

  const int c0 = blockIdx.x * 128;  // gate col base (0..I)
  const int r0 = blockIdx.y * 128;  // row base
  const int e = r0 >> 9;
  if ((r0 & (CAP - 1)) >= min(counts[e], CAP)) return;  // fully-padded tile

  const int tid = threadIdx.x;
  const int lane = tid & 63;
  const int wid = tid >> 6;
  const int wr = wid >> 1, wc = wid & 1;
  const int ml = lane & 15, kg = lane >> 4;

  const float* bg_base = gup + (size_t)e * (2 * I_DIM * H_DIM) + (size_t)c0 * H_DIM;
  const float* bu_base = bg_base + (size_t)I_DIM * H_DIM;

  float4v accg[4][4] = {};
  float4v accu[4][4] = {};

  for (int kk = 0; kk < H_DIM; kk += 32) {
    // A tile: 512 16B-chunks, async direct-to-LDS (layout forced contiguous by DMA)
#pragma unroll
    for (int q = 0; q < 2; ++q) {
      const unsigned short* g = xd + (size_t)(r0 + ((q * 256 + wid * 64) & 127)) * H_DIM +
                                kk + ((q * 256 + wid * 64) >> 7) * 8 + (lane & 63) * 0;
      // recompute per-chunk addr: ch = q*256 + wid*64 + lane
      int ch = q * 256 + wid * 64 + lane;
      int kc = ch >> 7, row = ch & 127;
      g = xd + (size_t)(r0 + row) * H_DIM + kk + kc * 8;
      unsigned short* l = lds_a + (size_t)(q * 256 + wid * 64) * 8;  // wave-uniform base
      GLOAD_LDS16(g, l);
    }
    // B tiles (fp32 -> bf16), swizzled LDS writes
#pragma unroll
    for (int q = 0; q < 2; ++q) {
      int c = q * 256 + tid;
      int n = c >> 2, kc = c & 3;
      int dst = SWZ(kc, n) * 8;
      {
        const float* g = bg_base + (size_t)n * H_DIM + kk + kc * 8;
        float4v f0 = *(const float4v*)g;
        float4v f1 = *(const float4v*)(g + 4);
        uint4v v;
        v.x = pack_bf2(f0.x, f0.y); v.y = pack_bf2(f0.z, f0.w);
        v.z = pack_bf2(f1.x, f1.y); v.w = pack_bf2(f1.z, f1.w);
        *(uint4v*)(lds_bg + dst) = v;
      }
      {
        const float* g = bu_base + (size_t)n * H_DIM + kk + kc * 8;
        float4v f0 = *(const float4v*)g;
        float4v f1 = *(const float4v*)(g + 4);
        uint4v v;
        v.x = pack_bf2(f0.x, f0.y); v.y = pack_bf2(f0.z, f0.w);
        v.z = pack_bf2(f1.x, f1.y); v.w = pack_bf2(f1.z, f1.w);
        *(uint4v*)(lds_bu + dst) = v;
      }
    }
    __syncthreads();

    short8 af[4], bgf[4], buf_[4];
#pragma unroll
    for (int mi = 0; mi < 4; ++mi)
      af[mi] = *(const short8*)(lds_a + (size_t)(kg * 128 + wr * 64 + mi * 16 + ml) * 8);
#pragma unroll
    for (int ni = 0; ni < 4; ++ni) {
      int sw = SWZ(kg, wc * 64 + ni * 16 + ml) * 8;
      bgf[ni] = *(const short8*)(lds_bg + sw);
      buf_[ni] = *(const short8*)(lds_bu + sw);
    }
#pragma unroll
    for (int mi = 0; mi < 4; ++mi)
#pragma unroll
      for (int ni = 0; ni < 4; ++ni) {
        accg[mi][ni] = __builtin_amdgcn_mfma_f32_16x16x32_bf16(af[mi], bgf[ni], accg[mi][ni], 0, 0, 0);
        accu[mi][ni] = __builtin_amdgcn_mfma_f32_16x16x32_bf16(af[mi], buf_[ni], accu[mi][ni], 0, 0, 0);
      }
    __syncthreads();
  }

  // epilogue: act = silu(g)*u, bf16
#pragma unroll
  for (int mi = 0; mi < 4; ++mi) {
    int row = r0 + wr * 64 + mi * 16 + kg * 4;
#pragma unroll
    for (int ni = 0; ni < 4; ++ni) {
      int col = c0 + wc * 64 + ni * 16 + ml;
#pragma unroll
      for (int rg = 0; rg < 4; ++rg) {
        float g = accg[mi][ni][rg];
        float u = accu[mi][ni][rg];
        float a = (g / (1.0f + __expf(-g))) * u;
        act[(size_t)(row + rg) * I_DIM + col] = f2bf_rne(a);
      }
    }
  }
}

// ---------------- GEMM2: act[NROWS,I] x down[E,H,I]^T -> yd[NROWS,H] bf16 ----
__global__ __launch_bounds__(256, 2) void k_gemm2(const unsigned short* __restrict__ act,
                                                  const float* __restrict__ dwn,
                                                  const int* __restrict__ counts,
                                                  unsigned short* __restrict__ yd) {
  __shared__ unsigned short lds_a[4 * 128 * 8];
  __shared__ unsigned short lds_b[4 * 128 * 8];

  const int c0 = blockIdx.x * 128;  // h col base (0..H)
  const int r0 = blockIdx.y * 128;  // row base
  const int e = r0 >> 9;
  if ((r0 & (CAP - 1)) >= min(counts[e], CAP)) return;

  const int tid = threadIdx.x;
  const int lane = tid & 63;
  const int wid = tid >> 6;
  const int wr = wid >> 1, wc = wid & 1;
  const int ml = lane & 15, kg = lane >> 4;

  const float* b_base = dwn + (size_t)e * (H_DIM * I_DIM) + (size_t)c0 * I_DIM;

  float4v acc[4][4] = {};

  for (int kk = 0; kk < I_DIM; kk += 32) {
#pragma unroll
    for (int q = 0; q < 2; ++q) {
      int ch = q * 256 + wid * 64 + lane;
      int kc = ch >> 7, row = ch & 127;
      const unsigned short* g = act + (size_t)(r0 + row) * I_DIM + kk + kc * 8;
      unsigned short* l = lds_a + (size_t)(q * 256 + wid * 64) * 8;
      GLOAD_LDS16(g, l);
    }
#pragma unroll
    for (int q = 0; q < 2; ++q) {
      int cc = q * 256 + tid;
      int n = cc >> 2, kc = cc & 3;
      const float* g = b_base + (size_t)n * I_DIM + kk + kc * 8;
      float4v f0 = *(const float4v*)g;
      float4v f1 = *(const float4v*)(g + 4);
      uint4v v;
      v.x = pack_bf2(f0.x, f0.y); v.y = pack_bf2(f0.z, f0.w);
      v.z = pack_bf2(f1.x, f1.y); v.w = pack_bf2(f1.z, f1.w);
      *(uint4v*)(lds_b + SWZ(kc, n) * 8) = v;
    }
    __syncthreads();

    short8 af[4], bf[4];
#pragma unroll
    for (int mi = 0; mi < 4; ++mi)
      af[mi] = *(const short8*)(lds_a + (size_t)(kg * 128 + wr * 64 + mi * 16 + ml) * 8);
#pragma unroll
    for (int ni = 0; ni < 4; ++ni)
      bf[ni] = *(const short8*)(lds_b + SWZ(kg, wc * 64 + ni * 16 + ml) * 8);
#pragma unroll
    for (int mi = 0; mi < 4; ++mi)
#pragma unroll
      for (int ni = 0; ni < 4; ++ni)
        acc[mi][ni] = __builtin_amdgcn_mfma_f32_16x16x32_bf16(af[mi], bf[ni], acc[mi][ni], 0, 0, 0);
    __syncthreads();
  }

  // epilogue: plain bf16 store (rows >= cnt hold zeros; never read by combine)
#pragma unroll
  for (int mi = 0; mi < 4; ++mi) {
    int row = r0 + wr * 64 + mi * 16 + kg * 4;
#pragma unroll
    for (int ni = 0; ni < 4; ++ni) {
      int col = c0 + wc * 64 + ni * 16 + ml;
#pragma unroll
      for (int rg = 0; rg < 4; ++rg)
        yd[(size_t)(row + rg) * H_DIM + col] = f2bf_rne(acc[mi][ni][rg]);
    }
  }
}

// ---------------- combine: out[t] = sum_k w[t,k] * yd[inv[t,k]] ----------------
__global__ void k_combine(const unsigned short* __restrict__ yd, const int* __restrict__ inv,
                          const float* __restrict__ wts, float* __restrict__ out) {
  const int t = blockIdx.x * 4 + (threadIdx.x >> 6);  // one wave per token
  const int lane = threadIdx.x & 63;
  const int i0 = 2 * t, i1 = 2 * t + 1;
  const int r0 = inv[i0], r1 = inv[i1];
  float o[8] = {0.f, 0.f, 0.f, 0.f, 0.f, 0.f, 0.f, 0.f};
  if (r0 >= 0) {
    float w = wts[i0];
    short8 y = *(const short8*)(yd + (size_t)r0 * H_DIM + lane * 8);
#pragma unroll
    for (int j = 0; j < 8; ++j) o[j] += w * bf2f((unsigned short)y[j]);
  }
  if (r1 >= 0) {
    float w = wts[i1];
    short8 y = *(const short8*)(yd + (size_t)r1 * H_DIM + lane * 8);
#pragma unroll
    for (int j = 0; j < 8; ++j) o[j] += w * bf2f((unsigned short)y[j]);
  }
  float4v v0 = {o[0], o[1], o[2], o[3]};
  float4v v1 = {o[4], o[5], o[6], o[7]};
  float4v* dst = (float4v*)(out + (size_t)t * H_DIM + lane * 8);
  dst[0] = v0;
  dst[1] = v1;
}

extern "C" void kernel_launch(void* const* d_in, const int* in_sizes, int n_in,
                              void* d_out, int out_size, void* d_ws, size_t ws_size,
                              hipStream_t stream) {
  const float* hs  = (const float*)d_in[0];  // [T,H]
  const int*   idx = (const int*)d_in[1];    // [T,K]
  const float* wts = (const float*)d_in[2];  // [T,K]
  const float* gup = (const float*)d_in[3];  // [E,2I,H]
  const float* dwn = (const float*)d_in[4];  // [E,H,I]
  float* out = (float*)d_out;                // [T,H]

  char* ws = (char*)d_ws;
  int* counts       = (int*)ws;                             // 128 B used
  int* inv          = (int*)(ws + 1024);                    // 32 KB
  int* slot_token   = (int*)(ws + 1024 + 32768);            // 64 KB
  unsigned short* xd  = (unsigned short*)(ws + 131072);     // 16 MB
  unsigned short* act = xd + (size_t)NROWS * H_DIM;         // 32 MB
  unsigned short* yd  = xd;  // xd is dead after gemm1; alias (16 MB)

  hipMemsetAsync(counts, 0, E_NUM * sizeof(int), stream);
  k_route<<<NPAIR / 256, 256, 0, stream>>>(idx, counts, slot_token, inv);
  k_gather<<<NROWS / 4, 256, 0, stream>>>(hs, counts, slot_token, xd);
  dim3 g1(I_DIM / 128, NROWS / 128);
  k_gemm1<<<g1, 256, 0, stream>>>(xd, gup, counts, act);
  dim3 g2(H_DIM / 128, NROWS / 128);
  k_gemm2<<<g2, 256, 0, stream>>>(act, dwn, counts, yd);
  k_combine<<<T_TOK / 4, 256, 0, stream>>>(yd, inv, wts, out);
}